// Round 1
// baseline (691.926 us; speedup 1.0000x reference)
//
#include <hip/hip_runtime.h>
#include <hip/hip_bf16.h>

#define N_ENTITY 100000
#define N_REL 50
#define DIM 64
#define N_HOP 2
#define N_MEM 32
#define BATCH 512
#define N_TRIPLE (N_HOP * BATCH * N_MEM)  // 32768
#define KGE_W 0.01f
#define L2_W 1e-7f

// ws layout (bytes)
#define SUMEXP_OFF 0      // 512 floats, zeroed by uemb_kernel
#define U16_OFF 4096      // 512*64 ushort (bf16 u embedding) = 65536 B
#define PART_OFF 69632    // 8192 float4 partials (kge_sig, h2, t2, r2)

typedef __attribute__((ext_vector_type(8))) short bf16x8;  // 8 bf16, 4 VGPRs
typedef __attribute__((ext_vector_type(4))) float f32x4;

__device__ __forceinline__ unsigned short f2bf(float f) {
    unsigned int u = __float_as_uint(f);
    u += 0x7fffu + ((u >> 16) & 1u);  // round-to-nearest-even
    return (unsigned short)(u >> 16);
}
__device__ __forceinline__ float bf2f(unsigned short h) {
    return __uint_as_float(((unsigned int)h) << 16);
}

// ---------------------------------------------------------------------------
// Kernel 1: u_emb[b,d] = sigmoid(mean_m entity[mh0[b,m]][d]); store as bf16.
// Also zeroes the per-row sumexp accumulators (thread d==0).
// ---------------------------------------------------------------------------
__global__ void uemb_kernel(const float* __restrict__ ent,
                            const int* __restrict__ mh0,
                            float* __restrict__ ws) {
    int b = blockIdx.x;
    int d = threadIdx.x;  // 0..63
    float acc = 0.f;
#pragma unroll
    for (int m = 0; m < N_MEM; ++m) {
        int idx = mh0[b * N_MEM + m];
        acc += ent[idx * DIM + d];
    }
    float u = 1.f / (1.f + __expf(-acc * (1.f / N_MEM)));
    unsigned short* u16 = (unsigned short*)((char*)ws + U16_OFF);
    u16[b * DIM + d] = f2bf(u);
    if (d == 0) ws[SUMEXP_OFF / 4 + b] = 0.f;
}

// ---------------------------------------------------------------------------
// Kernel 2: scores GEMM [512 x 100000] = u_bf16 @ W^T + bias, bf16 MFMA,
// 128x128 block tile, K=64 single pass. Fused per-row partial sum(exp(score))
// via 16-lane shuffle reduce + atomicAdd (scores ~ +-1.5, no max needed).
// ---------------------------------------------------------------------------
#define BM 128
#define BN 128
#define LDT 72  // padded LDS row stride in ushorts (+16B breaks bank aliasing)

__global__ __launch_bounds__(256, 2)
void gemm_kernel(const float* __restrict__ W, const float* __restrict__ bias,
                 const void* __restrict__ wsv, float* __restrict__ out_scores,
                 float* __restrict__ sumexp) {
    __shared__ unsigned short Als[BM * LDT];
    __shared__ unsigned short Bls[BN * LDT];
    const unsigned short* u16 = (const unsigned short*)((const char*)wsv + U16_OFF);
    int t = threadIdx.x;
    int n0 = blockIdx.x * BN;
    int bm = blockIdx.y * BM;

    // stage A: 128x64 bf16 tile of u (already bf16 in ws)
#pragma unroll
    for (int c = 0; c < 8; ++c) {
        int l = (t + c * 256) * 4;       // ushort index in 128*64 tile
        int row = l >> 6, col = l & 63;
        ushort4 v = *(const ushort4*)&u16[(bm + row) * DIM + col];
        *(ushort4*)&Als[row * LDT + col] = v;
    }
    // stage B: 128x64 W rows, fp32 -> bf16
#pragma unroll
    for (int c = 0; c < 8; ++c) {
        int l = (t + c * 256) * 4;       // float index in 128*64 tile
        int row = l >> 6, col = l & 63;
        int e = n0 + row;
        float4 f = make_float4(0.f, 0.f, 0.f, 0.f);
        if (e < N_ENTITY) f = *(const float4*)&W[(size_t)e * DIM + col];
        ushort4 v;
        v.x = f2bf(f.x); v.y = f2bf(f.y); v.z = f2bf(f.z); v.w = f2bf(f.w);
        *(ushort4*)&Bls[row * LDT + col] = v;
    }
    __syncthreads();

    int lane = t & 63, w = t >> 6;
    int wm = (w >> 1) * 64, wn = (w & 1) * 64;  // 2x2 waves of 64x64

    bf16x8 af[4][2], bfg[4][2];
#pragma unroll
    for (int mt = 0; mt < 4; ++mt)
#pragma unroll
        for (int k0 = 0; k0 < 2; ++k0)
            af[mt][k0] = *(const bf16x8*)&Als[(wm + mt * 16 + (lane & 15)) * LDT +
                                              k0 * 32 + (lane >> 4) * 8];
#pragma unroll
    for (int nt = 0; nt < 4; ++nt)
#pragma unroll
        for (int k0 = 0; k0 < 2; ++k0)
            bfg[nt][k0] = *(const bf16x8*)&Bls[(wn + nt * 16 + (lane & 15)) * LDT +
                                               k0 * 32 + (lane >> 4) * 8];

    f32x4 acc[4][4];
#pragma unroll
    for (int mt = 0; mt < 4; ++mt)
#pragma unroll
        for (int nt = 0; nt < 4; ++nt)
            acc[mt][nt] = (f32x4){0.f, 0.f, 0.f, 0.f};

#pragma unroll
    for (int mt = 0; mt < 4; ++mt)
#pragma unroll
        for (int nt = 0; nt < 4; ++nt) {
            acc[mt][nt] = __builtin_amdgcn_mfma_f32_16x16x32_bf16(
                af[mt][0], bfg[nt][0], acc[mt][nt], 0, 0, 0);
            acc[mt][nt] = __builtin_amdgcn_mfma_f32_16x16x32_bf16(
                af[mt][1], bfg[nt][1], acc[mt][nt], 0, 0, 0);
        }

    // epilogue: + bias, store, fused partial sum(exp) per row
    float bv[4];
#pragma unroll
    for (int nt = 0; nt < 4; ++nt) {
        int col = n0 + wn + nt * 16 + (lane & 15);
        bv[nt] = (col < N_ENTITY) ? bias[col] : 0.f;
    }
#pragma unroll
    for (int mt = 0; mt < 4; ++mt) {
#pragma unroll
        for (int i = 0; i < 4; ++i) {
            int grow = bm + wm + mt * 16 + (lane >> 4) * 4 + i;
            size_t rowbase = (size_t)grow * N_ENTITY;
            float rsum = 0.f;
#pragma unroll
            for (int nt = 0; nt < 4; ++nt) {
                int col = n0 + wn + nt * 16 + (lane & 15);
                float s = acc[mt][nt][i] + bv[nt];
                if (col < N_ENTITY) {
                    out_scores[rowbase + col] = s;
                    rsum += __expf(s);
                }
            }
            // reduce across the 16-lane group (all share the same row)
            rsum += __shfl_xor(rsum, 1);
            rsum += __shfl_xor(rsum, 2);
            rsum += __shfl_xor(rsum, 4);
            rsum += __shfl_xor(rsum, 8);
            if ((lane & 15) == 0) atomicAdd(&sumexp[grow], rsum);
        }
    }
}

// ---------------------------------------------------------------------------
// Kernel 3: per-triple h^T R t + fused l2 sums + sigmoid sum for kge.
// One wave per triple. Lane l accumulates v_e for e = (l&15)*4..+3 over
// d in {4*it + (l>>4)}; R rows read as coalesced float4 (1 KB / instr).
// ---------------------------------------------------------------------------
__global__ __launch_bounds__(256)
void hrt_kernel(const float* __restrict__ ent, const float* __restrict__ rel,
                const int* __restrict__ mh, const int* __restrict__ mr,
                const int* __restrict__ mtt, float4* __restrict__ partials) {
    __shared__ float red[4][4];
    int lane = threadIdx.x & 63, w = threadIdx.x >> 6;
    int tri = blockIdx.x * 4 + w;
    int hi = mh[tri], ri = mr[tri], ti = mtt[tri];
    float hv = ent[hi * DIM + lane];
    float4 t4 = *(const float4*)&ent[ti * DIM + (lane & 15) * 4];
    const float* Rp = rel + (size_t)ri * DIM * DIM;
    float a0 = 0.f, a1 = 0.f, a2 = 0.f, a3 = 0.f, r2 = 0.f;
#pragma unroll
    for (int it = 0; it < 16; ++it) {
        int d = it * 4 + (lane >> 4);
        float hd = __shfl(hv, d);
        float4 rv = *(const float4*)&Rp[d * DIM + (lane & 15) * 4];
        a0 += hd * rv.x; a1 += hd * rv.y; a2 += hd * rv.z; a3 += hd * rv.w;
        r2 += rv.x * rv.x + rv.y * rv.y + rv.z * rv.z + rv.w * rv.w;
    }
    float part = a0 * t4.x + a1 * t4.y + a2 * t4.z + a3 * t4.w;
    float h2 = hv * hv;
    float t2 = (t4.x * t4.x + t4.y * t4.y + t4.z * t4.z + t4.w * t4.w) * 0.25f;
#pragma unroll
    for (int m = 32; m >= 1; m >>= 1) {
        part += __shfl_xor(part, m);
        h2 += __shfl_xor(h2, m);
        t2 += __shfl_xor(t2, m);
        r2 += __shfl_xor(r2, m);
    }
    if (lane == 0) {
        red[w][0] = 1.f / (1.f + __expf(-part));  // sigmoid(hRt)
        red[w][1] = h2;
        red[w][2] = t2;
        red[w][3] = r2;
    }
    __syncthreads();
    if (threadIdx.x == 0) {
        float4 o;
        o.x = red[0][0] + red[1][0] + red[2][0] + red[3][0];
        o.y = red[0][1] + red[1][1] + red[2][1] + red[3][1];
        o.z = red[0][2] + red[1][2] + red[2][2] + red[3][2];
        o.w = red[0][3] + red[1][3] + red[2][3] + red[3][3];
        partials[blockIdx.x] = o;
    }
}

// ---------------------------------------------------------------------------
// Kernel 4: assemble scalars. Item scores recomputed with the same bf16
// rounding as the GEMM; base = mean(log(sumexp) - score_item); reduce hrt
// partials; write [loss, base, kge, l2] to out[0..3].
// ---------------------------------------------------------------------------
__global__ __launch_bounds__(512)
void final_kernel(const float* __restrict__ W, const float* __restrict__ bias,
                  const int* __restrict__ items, const void* __restrict__ wsv,
                  float* __restrict__ out) {
    __shared__ float sitem[BATCH];
    __shared__ float redA[8];
    __shared__ float4 redB[8];
    const float* sumexp = (const float*)wsv;
    const unsigned short* u16 = (const unsigned short*)((const char*)wsv + U16_OFF);
    const float4* parts = (const float4*)((const char*)wsv + PART_OFF);
    int t = threadIdx.x, lane = t & 63, w = t >> 6;

    // phase A: item scores — wave w handles rows w*64 .. w*64+63
    for (int rr = 0; rr < 64; ++rr) {
        int b = w * 64 + rr;
        int item = items[b];
        float wv = bf2f(f2bf(W[(size_t)item * DIM + lane]));
        float uv = bf2f(u16[b * DIM + lane]);
        float p = uv * wv;
#pragma unroll
        for (int m = 32; m >= 1; m >>= 1) p += __shfl_xor(p, m);
        if (lane == 0) sitem[b] = p + bias[item];
    }
    __syncthreads();

    // phase B: base loss contribution per row
    float lb = logf(sumexp[t]) - sitem[t];
#pragma unroll
    for (int m = 32; m >= 1; m >>= 1) lb += __shfl_xor(lb, m);
    if (lane == 0) redA[w] = lb;

    // phase C: reduce hrt partials (8192 float4)
    float4 lp = make_float4(0.f, 0.f, 0.f, 0.f);
    for (int i = t; i < N_TRIPLE / 4; i += 512) {
        float4 v = parts[i];
        lp.x += v.x; lp.y += v.y; lp.z += v.z; lp.w += v.w;
    }
#pragma unroll
    for (int m = 32; m >= 1; m >>= 1) {
        lp.x += __shfl_xor(lp.x, m);
        lp.y += __shfl_xor(lp.y, m);
        lp.z += __shfl_xor(lp.z, m);
        lp.w += __shfl_xor(lp.w, m);
    }
    if (lane == 0) redB[w] = lp;
    __syncthreads();

    if (t == 0) {
        float base = 0.f;
        float4 q = make_float4(0.f, 0.f, 0.f, 0.f);
        for (int i = 0; i < 8; ++i) {
            base += redA[i];
            q.x += redB[i].x; q.y += redB[i].y; q.z += redB[i].z; q.w += redB[i].w;
        }
        base *= (1.f / BATCH);
        float kge = -KGE_W * (q.x / (float)(BATCH * N_MEM));
        float l2 = L2_W * (q.y + q.z + q.w);
        out[0] = base + kge + l2;
        out[1] = base;
        out[2] = kge;
        out[3] = l2;
    }
}

// ---------------------------------------------------------------------------
extern "C" void kernel_launch(void* const* d_in, const int* in_sizes, int n_in,
                              void* d_out, int out_size, void* d_ws, size_t ws_size,
                              hipStream_t stream) {
    const float* ent  = (const float*)d_in[0];
    const float* rel  = (const float*)d_in[1];
    const float* W    = (const float*)d_in[2];
    const float* bias = (const float*)d_in[3];
    const int* items  = (const int*)d_in[4];
    // d_in[5] labels: unused by the reference loss
    const int* mh = (const int*)d_in[6];
    const int* mr = (const int*)d_in[7];
    const int* mt = (const int*)d_in[8];
    float* out = (float*)d_out;
    float* scores = out + 4;  // outputs: loss, base, kge, l2, scores[512*100000]
    float* ws = (float*)d_ws;
    float* sumexp = ws + SUMEXP_OFF / 4;
    float4* partials = (float4*)((char*)d_ws + PART_OFF);

    uemb_kernel<<<BATCH, DIM, 0, stream>>>(ent, mh, ws);
    dim3 g((N_ENTITY + BN - 1) / BN, BATCH / BM);
    gemm_kernel<<<g, 256, 0, stream>>>(W, bias, d_ws, scores, sumexp);
    hrt_kernel<<<N_TRIPLE / 4, 256, 0, stream>>>(ent, rel, mh, mr, mt, partials);
    final_kernel<<<1, 512, 0, stream>>>(W, bias, items, d_ws, out);
}

// Round 2
// 359.317 us; speedup vs baseline: 1.9257x; 1.9257x over previous
//
#include <hip/hip_runtime.h>
#include <hip/hip_bf16.h>

#define N_ENTITY 100000
#define N_REL 50
#define DIM 64
#define N_HOP 2
#define N_MEM 32
#define BATCH 512
#define N_TRIPLE (N_HOP * BATCH * N_MEM)  // 32768
#define KGE_W 0.01f
#define L2_W 1e-7f

#define BM 128
#define BN 128
#define NBX ((N_ENTITY + BN - 1) / BN)  // 782
#define LDT 72  // padded LDS row stride in ushorts

// ws layout (bytes)
#define U16_OFF 0                         // 512*64 ushort = 65536
#define HRT_OFF 65536                     // 4096 float4 = 65536
#define SE_OFF 131072                     // 512*782 float = 1601536
#define LB_OFF (SE_OFF + BATCH * NBX * 4) // 512 float

typedef __attribute__((ext_vector_type(8))) short bf16x8;
typedef __attribute__((ext_vector_type(4))) float f32x4;

__device__ __forceinline__ unsigned short f2bf(float f) {
    unsigned int u = __float_as_uint(f);
    u += 0x7fffu + ((u >> 16) & 1u);  // RNE
    return (unsigned short)(u >> 16);
}
__device__ __forceinline__ float bf2f(unsigned short h) {
    return __uint_as_float(((unsigned int)h) << 16);
}

// ---------------------------------------------------------------------------
// Kernel 1: u_emb[b,d] = sigmoid(mean_m entity[mh0[b,m]][d]) as bf16 in ws.
// ---------------------------------------------------------------------------
__global__ void uemb_kernel(const float* __restrict__ ent,
                            const int* __restrict__ mh0,
                            void* __restrict__ wsv) {
    int b = blockIdx.x;
    int d = threadIdx.x;  // 0..63
    float acc = 0.f;
#pragma unroll
    for (int m = 0; m < N_MEM; ++m) {
        int idx = mh0[b * N_MEM + m];
        acc += ent[idx * DIM + d];
    }
    float u = 1.f / (1.f + __expf(-acc * (1.f / N_MEM)));
    unsigned short* u16 = (unsigned short*)((char*)wsv + U16_OFF);
    u16[b * DIM + d] = f2bf(u);
}

// ---------------------------------------------------------------------------
// Kernel 2: scores = u_bf16 @ W^T + bias (bf16 MFMA, 128x128 tile, K=64).
// Fused per-row partial sum(exp(score)) — NO global atomics (fp32 atomicAdd
// lowers to a CAS loop; 800k CAS on 512 addrs serialized the whole memory
// pipe in R1). Partials go to LDS, then one plain store per row per block.
// ---------------------------------------------------------------------------
__global__ __launch_bounds__(256, 2)
void gemm_kernel(const float* __restrict__ W, const float* __restrict__ bias,
                 void* __restrict__ wsv, float* __restrict__ out_scores) {
    __shared__ unsigned short Als[BM * LDT];
    __shared__ unsigned short Bls[BN * LDT];
    __shared__ float rowred[BM][2];
    const unsigned short* u16 = (const unsigned short*)((const char*)wsv + U16_OFF);
    float* separt = (float*)((char*)wsv + SE_OFF);
    int t = threadIdx.x;
    int n0 = blockIdx.x * BN;
    int bm = blockIdx.y * BM;

#pragma unroll
    for (int c = 0; c < 8; ++c) {
        int l = (t + c * 256) * 4;
        int row = l >> 6, col = l & 63;
        ushort4 v = *(const ushort4*)&u16[(bm + row) * DIM + col];
        *(ushort4*)&Als[row * LDT + col] = v;
    }
#pragma unroll
    for (int c = 0; c < 8; ++c) {
        int l = (t + c * 256) * 4;
        int row = l >> 6, col = l & 63;
        int e = n0 + row;
        float4 f = make_float4(0.f, 0.f, 0.f, 0.f);
        if (e < N_ENTITY) f = *(const float4*)&W[(size_t)e * DIM + col];
        ushort4 v;
        v.x = f2bf(f.x); v.y = f2bf(f.y); v.z = f2bf(f.z); v.w = f2bf(f.w);
        *(ushort4*)&Bls[row * LDT + col] = v;
    }
    __syncthreads();

    int lane = t & 63, w = t >> 6;
    int wm = (w >> 1) * 64, wn = (w & 1) * 64;

    bf16x8 af[4][2], bfg[4][2];
#pragma unroll
    for (int mt = 0; mt < 4; ++mt)
#pragma unroll
        for (int k0 = 0; k0 < 2; ++k0)
            af[mt][k0] = *(const bf16x8*)&Als[(wm + mt * 16 + (lane & 15)) * LDT +
                                              k0 * 32 + (lane >> 4) * 8];
#pragma unroll
    for (int nt = 0; nt < 4; ++nt)
#pragma unroll
        for (int k0 = 0; k0 < 2; ++k0)
            bfg[nt][k0] = *(const bf16x8*)&Bls[(wn + nt * 16 + (lane & 15)) * LDT +
                                               k0 * 32 + (lane >> 4) * 8];

    f32x4 acc[4][4];
#pragma unroll
    for (int mt = 0; mt < 4; ++mt)
#pragma unroll
        for (int nt = 0; nt < 4; ++nt)
            acc[mt][nt] = (f32x4){0.f, 0.f, 0.f, 0.f};

#pragma unroll
    for (int mt = 0; mt < 4; ++mt)
#pragma unroll
        for (int nt = 0; nt < 4; ++nt) {
            acc[mt][nt] = __builtin_amdgcn_mfma_f32_16x16x32_bf16(
                af[mt][0], bfg[nt][0], acc[mt][nt], 0, 0, 0);
            acc[mt][nt] = __builtin_amdgcn_mfma_f32_16x16x32_bf16(
                af[mt][1], bfg[nt][1], acc[mt][nt], 0, 0, 0);
        }

    float bv[4];
#pragma unroll
    for (int nt = 0; nt < 4; ++nt) {
        int col = n0 + wn + nt * 16 + (lane & 15);
        bv[nt] = (col < N_ENTITY) ? bias[col] : 0.f;
    }
#pragma unroll
    for (int mt = 0; mt < 4; ++mt) {
#pragma unroll
        for (int i = 0; i < 4; ++i) {
            int lr = wm + mt * 16 + (lane >> 4) * 4 + i;  // local row 0..127
            size_t rowbase = (size_t)(bm + lr) * N_ENTITY;
            float rsum = 0.f;
#pragma unroll
            for (int nt = 0; nt < 4; ++nt) {
                int col = n0 + wn + nt * 16 + (lane & 15);
                float s = acc[mt][nt][i] + bv[nt];
                if (col < N_ENTITY) {
                    out_scores[rowbase + col] = s;
                    rsum += __expf(s);
                }
            }
            rsum += __shfl_xor(rsum, 1);
            rsum += __shfl_xor(rsum, 2);
            rsum += __shfl_xor(rsum, 4);
            rsum += __shfl_xor(rsum, 8);
            if ((lane & 15) == 0) rowred[lr][w & 1] = rsum;
        }
    }
    __syncthreads();
    if (t < BM) {
        float s = rowred[t][0] + rowred[t][1];
        separt[(size_t)(bm + t) * NBX + blockIdx.x] = s;
    }
}

// ---------------------------------------------------------------------------
// Kernel 3: per-triple h^T R t + fused l2 sums + sigmoid for kge.
// 512 threads = 8 triples/block -> 4096 partial float4s.
// ---------------------------------------------------------------------------
__global__ __launch_bounds__(512)
void hrt_kernel(const float* __restrict__ ent, const float* __restrict__ rel,
                const int* __restrict__ mh, const int* __restrict__ mr,
                const int* __restrict__ mtt, float4* __restrict__ partials) {
    __shared__ float red[8][4];
    int lane = threadIdx.x & 63, w = threadIdx.x >> 6;
    int tri = blockIdx.x * 8 + w;
    int hi = mh[tri], ri = mr[tri], ti = mtt[tri];
    float hv = ent[hi * DIM + lane];
    float4 t4 = *(const float4*)&ent[ti * DIM + (lane & 15) * 4];
    const float* Rp = rel + (size_t)ri * DIM * DIM;
    float a0 = 0.f, a1 = 0.f, a2 = 0.f, a3 = 0.f, r2 = 0.f;
#pragma unroll
    for (int it = 0; it < 16; ++it) {
        int d = it * 4 + (lane >> 4);
        float hd = __shfl(hv, d);
        float4 rv = *(const float4*)&Rp[d * DIM + (lane & 15) * 4];
        a0 += hd * rv.x; a1 += hd * rv.y; a2 += hd * rv.z; a3 += hd * rv.w;
        r2 += rv.x * rv.x + rv.y * rv.y + rv.z * rv.z + rv.w * rv.w;
    }
    float part = a0 * t4.x + a1 * t4.y + a2 * t4.z + a3 * t4.w;
    float h2 = hv * hv;
    float t2 = (t4.x * t4.x + t4.y * t4.y + t4.z * t4.z + t4.w * t4.w) * 0.25f;
#pragma unroll
    for (int m = 32; m >= 1; m >>= 1) {
        part += __shfl_xor(part, m);
        h2 += __shfl_xor(h2, m);
        t2 += __shfl_xor(t2, m);
        r2 += __shfl_xor(r2, m);
    }
    if (lane == 0) {
        red[w][0] = 1.f / (1.f + __expf(-part));
        red[w][1] = h2;
        red[w][2] = t2;
        red[w][3] = r2;
    }
    __syncthreads();
    if (threadIdx.x == 0) {
        float4 o = make_float4(0.f, 0.f, 0.f, 0.f);
#pragma unroll
        for (int k = 0; k < 8; ++k) {
            o.x += red[k][0]; o.y += red[k][1];
            o.z += red[k][2]; o.w += red[k][3];
        }
        partials[blockIdx.x] = o;
    }
}

// ---------------------------------------------------------------------------
// Kernel 4: per-row: sumexp = sum of 782 block partials; item score via
// bf16-rounded dot (matches GEMM numerics); lb[row] = log(se) - s_item.
// ---------------------------------------------------------------------------
__global__ __launch_bounds__(256)
void sereduce_kernel(const float* __restrict__ W, const float* __restrict__ bias,
                     const int* __restrict__ items, void* __restrict__ wsv) {
    __shared__ float ws4[4];
    int row = blockIdx.x;
    int t = threadIdx.x, lane = t & 63, w = t >> 6;
    const float* sp = (const float*)((const char*)wsv + SE_OFF) + (size_t)row * NBX;
    const unsigned short* u16 = (const unsigned short*)((const char*)wsv + U16_OFF);
    float* lb = (float*)((char*)wsv + LB_OFF);

    float s = 0.f;
    for (int i = t; i < NBX; i += 256) s += sp[i];
#pragma unroll
    for (int m = 32; m >= 1; m >>= 1) s += __shfl_xor(s, m);
    if (lane == 0) ws4[w] = s;
    __syncthreads();

    if (w == 0) {
        int item = items[row];
        float wv = bf2f(f2bf(W[(size_t)item * DIM + lane]));
        float uv = bf2f(u16[row * DIM + lane]);
        float p = uv * wv;
#pragma unroll
        for (int m = 32; m >= 1; m >>= 1) p += __shfl_xor(p, m);
        if (lane == 0) {
            float se = ws4[0] + ws4[1] + ws4[2] + ws4[3];
            lb[row] = logf(se) - (p + bias[item]);
        }
    }
}

// ---------------------------------------------------------------------------
// Kernel 5: final scalars.
// ---------------------------------------------------------------------------
__global__ __launch_bounds__(512)
void final_kernel(const void* __restrict__ wsv, float* __restrict__ out) {
    __shared__ float redA[8];
    __shared__ float4 redB[8];
    const float* lb = (const float*)((const char*)wsv + LB_OFF);
    const float4* parts = (const float4*)((const char*)wsv + HRT_OFF);
    int t = threadIdx.x, lane = t & 63, w = t >> 6;

    float b = lb[t];
#pragma unroll
    for (int m = 32; m >= 1; m >>= 1) b += __shfl_xor(b, m);
    if (lane == 0) redA[w] = b;

    float4 lp = make_float4(0.f, 0.f, 0.f, 0.f);
    for (int i = t; i < N_TRIPLE / 8; i += 512) {
        float4 v = parts[i];
        lp.x += v.x; lp.y += v.y; lp.z += v.z; lp.w += v.w;
    }
#pragma unroll
    for (int m = 32; m >= 1; m >>= 1) {
        lp.x += __shfl_xor(lp.x, m);
        lp.y += __shfl_xor(lp.y, m);
        lp.z += __shfl_xor(lp.z, m);
        lp.w += __shfl_xor(lp.w, m);
    }
    if (lane == 0) redB[w] = lp;
    __syncthreads();

    if (t == 0) {
        float base = 0.f;
        float4 q = make_float4(0.f, 0.f, 0.f, 0.f);
        for (int i = 0; i < 8; ++i) {
            base += redA[i];
            q.x += redB[i].x; q.y += redB[i].y; q.z += redB[i].z; q.w += redB[i].w;
        }
        base *= (1.f / BATCH);
        float kge = -KGE_W * (q.x / (float)(BATCH * N_MEM));
        float l2 = L2_W * (q.y + q.z + q.w);
        out[0] = base + kge + l2;
        out[1] = base;
        out[2] = kge;
        out[3] = l2;
    }
}

// ---------------------------------------------------------------------------
extern "C" void kernel_launch(void* const* d_in, const int* in_sizes, int n_in,
                              void* d_out, int out_size, void* d_ws, size_t ws_size,
                              hipStream_t stream) {
    const float* ent  = (const float*)d_in[0];
    const float* rel  = (const float*)d_in[1];
    const float* W    = (const float*)d_in[2];
    const float* bias = (const float*)d_in[3];
    const int* items  = (const int*)d_in[4];
    const int* mh = (const int*)d_in[6];
    const int* mr = (const int*)d_in[7];
    const int* mt = (const int*)d_in[8];
    float* out = (float*)d_out;
    float* scores = out + 4;  // outputs: loss, base, kge, l2, scores[512*100000]
    float4* hrt_parts = (float4*)((char*)d_ws + HRT_OFF);

    uemb_kernel<<<BATCH, DIM, 0, stream>>>(ent, mh, d_ws);
    dim3 g(NBX, BATCH / BM);
    gemm_kernel<<<g, 256, 0, stream>>>(W, bias, d_ws, scores);
    hrt_kernel<<<N_TRIPLE / 8, 512, 0, stream>>>(ent, rel, mh, mr, mt, hrt_parts);
    sereduce_kernel<<<BATCH, 256, 0, stream>>>(W, bias, items, d_ws);
    final_kernel<<<1, 512, 0, stream>>>(d_ws, out);
}